// Round 4
// baseline (1087.542 us; speedup 1.0000x reference)
//
#include <hip/hip_runtime.h>
#include <hip/hip_fp16.h>

#define BB 256
#define TT 2000
#define HH 100
#define II 4
#define CH 8              // time-chunk (register-buffered I/O)
#define NCHUNK (TT / CH)  // 250
#define KSLOT 128         // padded k slots (fp16 elements), 4 slices x 32

typedef _Float16 half2v __attribute__((ext_vector_type(2)));
typedef unsigned int uintv8 __attribute__((ext_vector_type(8)));
typedef __attribute__((ext_vector_type(8))) unsigned short ushort8_t;

static constexpr float kC1 = 0.9f;   // 1 - dt/tau
static constexpr float kC2 = 0.1f;   // dt/tau
static constexpr float kEPS = 1e-5f;

// tanh via v_exp_f32 + v_rcp_f32 (~40 cyc incl quarter-rate transcendentals)
__device__ __forceinline__ float fast_tanh(float x) {
    const float xc = fminf(fmaxf(x, -15.f), 15.f);
    const float e  = __builtin_amdgcn_exp2f(xc * 2.88539008177793f); // 2*log2(e)
    return (e - 1.f) * __builtin_amdgcn_rcpf(e + 1.f);
}

__device__ __forceinline__ half2v u2h(unsigned int u) {
    union { unsigned int u; half2v h; } c; c.u = u; return c.h;
}
__device__ __forceinline__ unsigned int pkh(float x, float y) {
    union { half2v h; unsigned int u; } c;
    c.h = half2v{(_Float16)x, (_Float16)y};
    return c.u;
}

#if __has_builtin(__builtin_amdgcn_fdot2)
#define DOT2(a, b, c) __builtin_amdgcn_fdot2((a), (b), (c), false)
#else
__device__ __forceinline__ float dot2_fb(half2v a, half2v b, float c) {
    return fmaf((float)a.y, (float)b.y, fmaf((float)a.x, (float)b.x, c));
}
#define DOT2(a, b, c) dot2_fb((a), (b), (c))
#endif

// ---------------------------------------------------------------------------
// Kernel 1: per-batch scan. 256 thr = 4 waves. Quad = (pair p of channels
// {2p,2p+1}) x (k-slice kg of 32 fp16 th values). Each lane reads ONE slice
// (4 x ds_read_b128) and dots it against BOTH channels' fp16 weights (reuse).
// Lane-selected channel cs = 2p + (kg&1) handles tanh/update/sigma/store.
// Raw s_barrier (no vmcnt drain) + chunked register-double-buffered I/O.
// ---------------------------------------------------------------------------
__global__ __launch_bounds__(256) void crnn_scan_kernel(
    const float* __restrict__ x, const float* __restrict__ Win,
    const float* __restrict__ Wh, const float* __restrict__ sigma,
    __half* __restrict__ out_buf, float* __restrict__ partials,
    float* __restrict__ d_out /* h_last at offset B*T */)
{
    const int b   = blockIdx.x;
    const int tid = threadIdx.x;
    const int p   = tid >> 2;          // channel-pair index 0..63
    const int kg  = tid & 3;           // k-slice group
    const bool act = (p < HH / 2);     // 50 active pairs
    const int pc  = act ? p : (HH / 2 - 1);
    const int c0  = 2 * pc, c1 = 2 * pc + 1;
    const int cs  = c0 + (kg & 1);     // this lane's own channel
    const bool wr = act && (kg < 2);   // unique writer per channel

    __shared__ unsigned int thb[2][KSLOT / 2];   // fp16 th, double-buffered
    for (int i = tid; i < KSLOT; i += 256) ((unsigned int*)thb)[i] = 0u;

    // W_hidden slice kg (k = kg*32 .. +31) for BOTH channels, packed half2
    const int k0 = kg * 32;
    uintv8 wa0, wa1, wb0, wb1;
#pragma unroll
    for (int i = 0; i < 8; ++i) {
        const int ka = k0 + 2 * i;          // pairs 0..7
        const int kb = k0 + 16 + 2 * i;     // pairs 8..15
        const float a0 = (ka < HH) ? Wh[(size_t)ka * HH + c0] : 0.f;
        const float a1 = (ka + 1 < HH) ? Wh[(size_t)(ka + 1) * HH + c0] : 0.f;
        const float a2 = (kb < HH) ? Wh[(size_t)kb * HH + c0] : 0.f;
        const float a3 = (kb + 1 < HH) ? Wh[(size_t)(kb + 1) * HH + c0] : 0.f;
        const float b0 = (ka < HH) ? Wh[(size_t)ka * HH + c1] : 0.f;
        const float b1 = (ka + 1 < HH) ? Wh[(size_t)(ka + 1) * HH + c1] : 0.f;
        const float b2 = (kb < HH) ? Wh[(size_t)kb * HH + c1] : 0.f;
        const float b3 = (kb + 1 < HH) ? Wh[(size_t)(kb + 1) * HH + c1] : 0.f;
        wa0[i] = pkh(a0, a1); wa1[i] = pkh(a2, a3);
        wb0[i] = pkh(b0, b1); wb1[i] = pkh(b2, b3);
    }

    const float win0 = Win[0 * HH + cs];
    const float win1 = Win[1 * HH + cs];
    const float win2 = Win[2 * HH + cs];
    const float win3 = Win[3 * HH + cs];

    const float* sig = sigma + (size_t)b * TT * HH + cs;
    const float* xp  = x + (size_t)b * TT * II;
    __half* op = out_buf + ((size_t)b * HH + cs) * TT;   // [B][H][T]

    float h = 0.f, bsum = 0.f, bsq = 0.f;
    float sA[CH], wA[CH], sB[CH], wB[CH];

    auto loadc = [&](int t0, float (&ss)[CH], float (&ww)[CH]) {
#pragma unroll
        for (int i = 0; i < CH; ++i) ss[i] = sig[(size_t)(t0 + i) * HH];
#pragma unroll
        for (int i = 0; i < CH; ++i) {
            const float4 xv = *(const float4*)(xp + (size_t)(t0 + i) * II);
            ww[i] = xv.x * win0 + xv.y * win1 + xv.z * win2 + xv.w * win3;
        }
    };

    auto run_chunk = [&](int t0, const float (&ss)[CH], const float (&ww)[CH]) {
        unsigned int hw[CH / 2];
#pragma unroll
        for (int i = 0; i < CH; ++i) {     // t0 even -> LDS buffer = i&1
            const float thv = fast_tanh(h);            // one chain, own channel
            if (wr) ((unsigned short*)thb[i & 1])[cs] =
                        (unsigned short)(pkh(thv, 0.f) & 0xffffu);
            asm volatile("s_waitcnt lgkmcnt(0)" ::: "memory");
            __builtin_amdgcn_s_barrier();
            asm volatile("" ::: "memory");

            // slice read: 4 x ds_read_b128 (16 half2)
            const uint4* tb = (const uint4*)thb[i & 1] + kg * 4;
            const uint4 r0 = tb[0], r1 = tb[1], r2 = tb[2], r3 = tb[3];

            // dots for both channels, 4 chains of depth 8
            float a0c, a1c, b0c, b1c;
            a0c = DOT2(u2h(r0.x), u2h(wa0[0]), 0.f);
            a1c = DOT2(u2h(r0.y), u2h(wa0[1]), 0.f);
            b0c = DOT2(u2h(r0.x), u2h(wb0[0]), 0.f);
            b1c = DOT2(u2h(r0.y), u2h(wb0[1]), 0.f);
            a0c = DOT2(u2h(r0.z), u2h(wa0[2]), a0c);
            a1c = DOT2(u2h(r0.w), u2h(wa0[3]), a1c);
            b0c = DOT2(u2h(r0.z), u2h(wb0[2]), b0c);
            b1c = DOT2(u2h(r0.w), u2h(wb0[3]), b1c);
            a0c = DOT2(u2h(r1.x), u2h(wa0[4]), a0c);
            a1c = DOT2(u2h(r1.y), u2h(wa0[5]), a1c);
            b0c = DOT2(u2h(r1.x), u2h(wb0[4]), b0c);
            b1c = DOT2(u2h(r1.y), u2h(wb0[5]), b1c);
            a0c = DOT2(u2h(r1.z), u2h(wa0[6]), a0c);
            a1c = DOT2(u2h(r1.w), u2h(wa0[7]), a1c);
            b0c = DOT2(u2h(r1.z), u2h(wb0[6]), b0c);
            b1c = DOT2(u2h(r1.w), u2h(wb0[7]), b1c);
            a0c = DOT2(u2h(r2.x), u2h(wa1[0]), a0c);
            a1c = DOT2(u2h(r2.y), u2h(wa1[1]), a1c);
            b0c = DOT2(u2h(r2.x), u2h(wb1[0]), b0c);
            b1c = DOT2(u2h(r2.y), u2h(wb1[1]), b1c);
            a0c = DOT2(u2h(r2.z), u2h(wa1[2]), a0c);
            a1c = DOT2(u2h(r2.w), u2h(wa1[3]), a1c);
            b0c = DOT2(u2h(r2.z), u2h(wb1[2]), b0c);
            b1c = DOT2(u2h(r2.w), u2h(wb1[3]), b1c);
            a0c = DOT2(u2h(r3.x), u2h(wa1[4]), a0c);
            a1c = DOT2(u2h(r3.y), u2h(wa1[5]), a1c);
            b0c = DOT2(u2h(r3.x), u2h(wb1[4]), b0c);
            b1c = DOT2(u2h(r3.y), u2h(wb1[5]), b1c);
            a0c = DOT2(u2h(r3.z), u2h(wa1[6]), a0c);
            a1c = DOT2(u2h(r3.w), u2h(wa1[7]), a1c);
            b0c = DOT2(u2h(r3.z), u2h(wb1[6]), b0c);
            b1c = DOT2(u2h(r3.w), u2h(wb1[7]), b1c);

            float s0 = a0c + a1c;          // partial dot, channel c0
            float s1 = b0c + b1c;          // partial dot, channel c1
            s0 += __shfl_xor(s0, 1, 64); s0 += __shfl_xor(s0, 2, 64);
            s1 += __shfl_xor(s1, 1, 64); s1 += __shfl_xor(s1, 2, 64);
            const float ssel = (kg & 1) ? s1 : s0;

            h = fmaf(kC1, h, kC2 * (ww[i] + ssel)) + ss[i];

            const unsigned int hb = pkh(h, 0.f) & 0xffffu;
            if ((i & 1) == 0) hw[i >> 1] = hb; else hw[i >> 1] |= hb << 16;
            bsum += h;
            bsq = fmaf(h, h, bsq);
        }
        if (wr) *(uint4*)(op + t0) = make_uint4(hw[0], hw[1], hw[2], hw[3]);
    };

    __syncthreads();            // LDS zero-init visible (one-time)
    loadc(0, sA, wA);
    for (int c = 0; c < NCHUNK; ++c) {
        const int t0 = c * CH;
        if ((c & 1) == 0) {
            if (c + 1 < NCHUNK) loadc(t0 + CH, sB, wB);
            run_chunk(t0, sA, wA);
        } else {
            if (c + 1 < NCHUNK) loadc(t0 + CH, sA, wA);
            run_chunk(t0, sB, wB);
        }
    }

    if (wr) {
        partials[b * (2 * HH) + cs]      = bsum;
        partials[b * (2 * HH) + HH + cs] = bsq;
        d_out[(size_t)BB * TT + b * HH + cs] = h;   // h_last [B,H]
    }
}

// ---------------------------------------------------------------------------
// Kernel 2: fold per-batch partials -> per-channel scale/shift. Tiny.
// ---------------------------------------------------------------------------
__global__ __launch_bounds__(512) void crnn_bnstats_kernel(
    const float* __restrict__ partials, const float* __restrict__ gamma,
    const float* __restrict__ beta, float* __restrict__ scsh)
{
    const int tid = threadIdx.x;
    const int j = tid >> 2, c = tid & 3;
    if (j >= HH) return;
    float sum = 0.f, sq = 0.f;
    for (int b = c; b < BB; b += 4) {
        sum += partials[b * 2 * HH + j];
        sq  += partials[b * 2 * HH + HH + j];
    }
    sum += __shfl_xor(sum, 1, 64); sum += __shfl_xor(sum, 2, 64);
    sq  += __shfl_xor(sq,  1, 64); sq  += __shfl_xor(sq,  2, 64);
    if (c == 0) {
        const float invN = 1.f / (float)((long)BB * TT);
        const float mean = sum * invN;
        const float var  = sq * invN - mean * mean;
        const float sc   = gamma[j] * rsqrtf(var + kEPS);
        scsh[j]      = sc;
        scsh[HH + j] = fmaf(-mean, sc, beta[j]);
    }
}

// ---------------------------------------------------------------------------
// Kernel 3: [B][H][T] layout -> thread owns 8 consecutive t's (16B loads),
// loops h with uniform (s_load) BN constants. Fully coalesced, no shuffles.
// ---------------------------------------------------------------------------
__global__ __launch_bounds__(256) void crnn_out_kernel(
    const __half* __restrict__ buf, const float* __restrict__ scsh,
    const float* __restrict__ fcw, const float* __restrict__ fcb,
    float* __restrict__ out)
{
    const int b   = blockIdx.x;
    const int tid = threadIdx.x;
    const bool a  = (tid < TT / 8);     // 250 active
    const int t0  = tid * 8;
    const __half* bp = buf + (size_t)b * HH * TT + t0;
    const float bias = fcb[0];

    float acc[8] = {0.f, 0.f, 0.f, 0.f, 0.f, 0.f, 0.f, 0.f};
    for (int hh = 0; hh < HH; ++hh) {
        const float sc = scsh[hh], sh = scsh[HH + hh], fw = fcw[hh];
        if (a) {
            const ushort8_t v = *(const ushort8_t*)(bp + (size_t)hh * TT);
#pragma unroll
            for (int e = 0; e < 8; ++e) {
                const float vf = __half2float(__ushort_as_half((unsigned short)v[e]));
                acc[e] = fmaf(fast_tanh(fmaf(vf, sc, sh)), fw, acc[e]);
            }
        }
    }
    if (a) {
        float4* o = (float4*)(out + (size_t)b * TT + t0);
        o[0] = make_float4(acc[0] + bias, acc[1] + bias, acc[2] + bias, acc[3] + bias);
        o[1] = make_float4(acc[4] + bias, acc[5] + bias, acc[6] + bias, acc[7] + bias);
    }
}

// ---------------------------------------------------------------------------
extern "C" void kernel_launch(void* const* d_in, const int* in_sizes, int n_in,
                              void* d_out, int out_size, void* d_ws, size_t ws_size,
                              hipStream_t stream)
{
    const float* x     = (const float*)d_in[0];
    const float* Win   = (const float*)d_in[1];
    const float* Wh    = (const float*)d_in[2];
    const float* sigma = (const float*)d_in[3];
    const float* gamma = (const float*)d_in[4];
    const float* beta  = (const float*)d_in[5];
    const float* fcw   = (const float*)d_in[6];
    const float* fcb   = (const float*)d_in[7];
    float* out = (float*)d_out;

    char* ws = (char*)d_ws;
    __half* out_buf = (__half*)ws;                                   // B*H*T fp16
    float* partials = (float*)(ws + (size_t)BB * TT * HH * sizeof(__half));
    float* scsh     = (float*)((char*)partials + (size_t)BB * 2 * HH * sizeof(float));

    crnn_scan_kernel<<<BB, 256, 0, stream>>>(x, Win, Wh, sigma, out_buf, partials, out);
    crnn_bnstats_kernel<<<1, 512, 0, stream>>>(partials, gamma, beta, scsh);
    crnn_out_kernel<<<BB, 256, 0, stream>>>(out_buf, scsh, fcw, fcb, out);
}

// Round 6
// 936.470 us; speedup vs baseline: 1.1613x; 1.1613x over previous
//
#include <hip/hip_runtime.h>
#include <hip/hip_fp16.h>

#define BB 256
#define TT 2000
#define HH 100
#define II 4
#define CH 8              // time-chunk (register-buffered I/O)
#define NCHUNK (TT / CH)  // 250
#define KSLOT 128         // padded k slots (fp16 elements), 4 slices x 32

typedef _Float16 half2v __attribute__((ext_vector_type(2)));
typedef unsigned int uintv8 __attribute__((ext_vector_type(8)));
typedef __attribute__((ext_vector_type(8))) unsigned short ushort8_t;

static constexpr float kC1 = 0.9f;   // 1 - dt/tau
static constexpr float kC2 = 0.1f;   // dt/tau
static constexpr float kEPS = 1e-5f;

// tanh via v_exp_f32 + v_rcp_f32 (~50 cyc chain, rel err ~1e-7)
__device__ __forceinline__ float fast_tanh(float x) {
    const float xc = fminf(fmaxf(x, -15.f), 15.f);
    const float e  = __builtin_amdgcn_exp2f(xc * 2.88539008177793f); // 2*log2(e)
    return (e - 1.f) * __builtin_amdgcn_rcpf(e + 1.f);
}

__device__ __forceinline__ half2v u2h(unsigned int u) {
    union { unsigned int u; half2v h; } c; c.u = u; return c.h;
}
__device__ __forceinline__ unsigned int pkh(float x, float y) {
    union { half2v h; unsigned int u; } c;
    c.h = half2v{(_Float16)x, (_Float16)y};
    return c.u;
}

// DPP quad_perm butterfly add: VALU-latency cross-lane (NOT ds_bpermute).
// CTRL 0xB1 = quad_perm [1,0,3,2] (xor 1); 0x4E = [2,3,0,1] (xor 2).
template <int CTRL>
__device__ __forceinline__ float qadd(float v) {
    return v + __int_as_float(__builtin_amdgcn_update_dpp(
        0, __float_as_int(v), CTRL, 0xF, 0xF, true));
}

#if __has_builtin(__builtin_amdgcn_fdot2)
#define DOT2(a, b, c) __builtin_amdgcn_fdot2((a), (b), (c), false)
#else
__device__ __forceinline__ float dot2_fb(half2v a, half2v b, float c) {
    return fmaf((float)a.y, (float)b.y, fmaf((float)a.x, (float)b.x, c));
}
#define DOT2(a, b, c) dot2_fb((a), (b), (c))
#endif

// ---------------------------------------------------------------------------
// Kernel 1: per-batch scan. 256 thr = 4 waves. Quad = (channel pair p) x
// (k-slice kg). Lane reads ONE 32-half th slice (4 x ds_read_b128), dots it
// against both channels' fp16 weights; quad-reduce via 3 DPP adds + cndmask.
// Raw s_barrier (no vmcnt drain) + chunked register-double-buffered I/O.
// ---------------------------------------------------------------------------
__global__ __launch_bounds__(256) void crnn_scan_kernel(
    const float* __restrict__ x, const float* __restrict__ Win,
    const float* __restrict__ Wh, const float* __restrict__ sigma,
    __half* __restrict__ out_buf, float* __restrict__ partials,
    float* __restrict__ d_out /* h_last at offset B*T */)
{
    const int b   = blockIdx.x;
    const int tid = threadIdx.x;
    const int p   = tid >> 2;          // channel-pair index 0..63
    const int kg  = tid & 3;           // k-slice group
    const bool act = (p < HH / 2);     // 50 active pairs
    const int pc  = act ? p : (HH / 2 - 1);
    const int c0  = 2 * pc, c1 = 2 * pc + 1;
    const int cs  = c0 + (kg & 1);     // this lane's own channel
    const bool wr = act && (kg < 2);   // unique writer per channel

    __shared__ unsigned int thb[2][KSLOT / 2];   // fp16 th, double-buffered
    for (int i = tid; i < KSLOT; i += 256) ((unsigned int*)thb)[i] = 0u;

    // W_hidden slice kg (k = kg*32 .. +31) for BOTH channels, packed half2
    const int k0 = kg * 32;
    uintv8 wa0, wa1, wb0, wb1;
#pragma unroll
    for (int i = 0; i < 8; ++i) {
        const int ka = k0 + 2 * i;          // pairs 0..7
        const int kb = k0 + 16 + 2 * i;     // pairs 8..15
        const float a0 = (ka < HH) ? Wh[(size_t)ka * HH + c0] : 0.f;
        const float a1 = (ka + 1 < HH) ? Wh[(size_t)(ka + 1) * HH + c0] : 0.f;
        const float a2 = (kb < HH) ? Wh[(size_t)kb * HH + c0] : 0.f;
        const float a3 = (kb + 1 < HH) ? Wh[(size_t)(kb + 1) * HH + c0] : 0.f;
        const float b0 = (ka < HH) ? Wh[(size_t)ka * HH + c1] : 0.f;
        const float b1 = (ka + 1 < HH) ? Wh[(size_t)(ka + 1) * HH + c1] : 0.f;
        const float b2 = (kb < HH) ? Wh[(size_t)kb * HH + c1] : 0.f;
        const float b3 = (kb + 1 < HH) ? Wh[(size_t)(kb + 1) * HH + c1] : 0.f;
        wa0[i] = pkh(a0, a1); wa1[i] = pkh(a2, a3);
        wb0[i] = pkh(b0, b1); wb1[i] = pkh(b2, b3);
    }

    const float win0 = Win[0 * HH + cs];
    const float win1 = Win[1 * HH + cs];
    const float win2 = Win[2 * HH + cs];
    const float win3 = Win[3 * HH + cs];

    const float* sig = sigma + (size_t)b * TT * HH + cs;
    const float* xp  = x + (size_t)b * TT * II;
    __half* op = out_buf + ((size_t)b * HH + cs) * TT;   // [B][H][T]

    float h = 0.f, bsum = 0.f, bsq = 0.f;
    float sA[CH], wA[CH], sB[CH], wB[CH];

    auto loadc = [&](int t0, float (&ss)[CH], float (&ww)[CH]) {
#pragma unroll
        for (int i = 0; i < CH; ++i) ss[i] = sig[(size_t)(t0 + i) * HH];
#pragma unroll
        for (int i = 0; i < CH; ++i) {
            const float4 xv = *(const float4*)(xp + (size_t)(t0 + i) * II);
            ww[i] = xv.x * win0 + xv.y * win1 + xv.z * win2 + xv.w * win3;
        }
    };

    auto run_chunk = [&](int t0, const float (&ss)[CH], const float (&ww)[CH]) {
        unsigned int hw[CH / 2];
#pragma unroll
        for (int i = 0; i < CH; ++i) {     // t0 even -> LDS buffer = i&1
            const float thv = fast_tanh(h);            // one chain, own channel
            if (wr) ((unsigned short*)thb[i & 1])[cs] =
                        (unsigned short)(pkh(thv, 0.f) & 0xffffu);
            asm volatile("s_waitcnt lgkmcnt(0)" ::: "memory");
            __builtin_amdgcn_s_barrier();
            asm volatile("" ::: "memory");

            // slice read: 4 x ds_read_b128 (16 half2)
            const uint4* tb = (const uint4*)thb[i & 1] + kg * 4;
            const uint4 r0 = tb[0], r1 = tb[1], r2 = tb[2], r3 = tb[3];

            // dots for both channels, 4 chains of depth 8
            float a0c, a1c, b0c, b1c;
            a0c = DOT2(u2h(r0.x), u2h(wa0[0]), 0.f);
            a1c = DOT2(u2h(r0.y), u2h(wa0[1]), 0.f);
            b0c = DOT2(u2h(r0.x), u2h(wb0[0]), 0.f);
            b1c = DOT2(u2h(r0.y), u2h(wb0[1]), 0.f);
            a0c = DOT2(u2h(r0.z), u2h(wa0[2]), a0c);
            a1c = DOT2(u2h(r0.w), u2h(wa0[3]), a1c);
            b0c = DOT2(u2h(r0.z), u2h(wb0[2]), b0c);
            b1c = DOT2(u2h(r0.w), u2h(wb0[3]), b1c);
            a0c = DOT2(u2h(r1.x), u2h(wa0[4]), a0c);
            a1c = DOT2(u2h(r1.y), u2h(wa0[5]), a1c);
            b0c = DOT2(u2h(r1.x), u2h(wb0[4]), b0c);
            b1c = DOT2(u2h(r1.y), u2h(wb0[5]), b1c);
            a0c = DOT2(u2h(r1.z), u2h(wa0[6]), a0c);
            a1c = DOT2(u2h(r1.w), u2h(wa0[7]), a1c);
            b0c = DOT2(u2h(r1.z), u2h(wb0[6]), b0c);
            b1c = DOT2(u2h(r1.w), u2h(wb0[7]), b1c);
            a0c = DOT2(u2h(r2.x), u2h(wa1[0]), a0c);
            a1c = DOT2(u2h(r2.y), u2h(wa1[1]), a1c);
            b0c = DOT2(u2h(r2.x), u2h(wb1[0]), b0c);
            b1c = DOT2(u2h(r2.y), u2h(wb1[1]), b1c);
            a0c = DOT2(u2h(r2.z), u2h(wa1[2]), a0c);
            a1c = DOT2(u2h(r2.w), u2h(wa1[3]), a1c);
            b0c = DOT2(u2h(r2.z), u2h(wb1[2]), b0c);
            b1c = DOT2(u2h(r2.w), u2h(wb1[3]), b1c);
            a0c = DOT2(u2h(r3.x), u2h(wa1[4]), a0c);
            a1c = DOT2(u2h(r3.y), u2h(wa1[5]), a1c);
            b0c = DOT2(u2h(r3.x), u2h(wb1[4]), b0c);
            b1c = DOT2(u2h(r3.y), u2h(wb1[5]), b1c);
            a0c = DOT2(u2h(r3.z), u2h(wa1[6]), a0c);
            a1c = DOT2(u2h(r3.w), u2h(wa1[7]), a1c);
            b0c = DOT2(u2h(r3.z), u2h(wb1[6]), b0c);
            b1c = DOT2(u2h(r3.w), u2h(wb1[7]), b1c);

            float s0 = a0c + a1c;          // lane-partial dot, channel c0
            float s1 = b0c + b1c;          // lane-partial dot, channel c1
            // DPP quad reduce: xor1 both, select own channel, xor2 once.
            const float t0s = qadd<0xB1>(s0);
            const float t1s = qadd<0xB1>(s1);
            const float sel = (kg & 1) ? t1s : t0s;
            const float ssel = qadd<0x4E>(sel);    // full dot for channel cs

            h = fmaf(kC1, h, kC2 * (ww[i] + ssel)) + ss[i];

            const unsigned int hb = pkh(h, 0.f) & 0xffffu;
            if ((i & 1) == 0) hw[i >> 1] = hb; else hw[i >> 1] |= hb << 16;
            bsum += h;
            bsq = fmaf(h, h, bsq);
        }
        if (wr) *(uint4*)(op + t0) = make_uint4(hw[0], hw[1], hw[2], hw[3]);
    };

    __syncthreads();            // LDS zero-init visible (one-time)
    loadc(0, sA, wA);
    for (int c = 0; c < NCHUNK; ++c) {
        const int t0 = c * CH;
        if ((c & 1) == 0) {
            if (c + 1 < NCHUNK) loadc(t0 + CH, sB, wB);
            run_chunk(t0, sA, wA);
        } else {
            if (c + 1 < NCHUNK) loadc(t0 + CH, sA, wA);
            run_chunk(t0, sB, wB);
        }
    }

    if (wr) {
        partials[b * (2 * HH) + cs]      = bsum;
        partials[b * (2 * HH) + HH + cs] = bsq;
        d_out[(size_t)BB * TT + b * HH + cs] = h;   // h_last [B,H]
    }
}

// ---------------------------------------------------------------------------
// Kernel 2: fold per-batch partials -> per-channel scale/shift. Tiny.
// ---------------------------------------------------------------------------
__global__ __launch_bounds__(512) void crnn_bnstats_kernel(
    const float* __restrict__ partials, const float* __restrict__ gamma,
    const float* __restrict__ beta, float* __restrict__ scsh)
{
    const int tid = threadIdx.x;
    const int j = tid >> 2, c = tid & 3;
    if (j >= HH) return;
    float sum = 0.f, sq = 0.f;
    for (int b = c; b < BB; b += 4) {
        sum += partials[b * 2 * HH + j];
        sq  += partials[b * 2 * HH + HH + j];
    }
    sum = qadd<0xB1>(sum); sum = qadd<0x4E>(sum);
    sq  = qadd<0xB1>(sq);  sq  = qadd<0x4E>(sq);
    if (c == 0) {
        const float invN = 1.f / (float)((long)BB * TT);
        const float mean = sum * invN;
        const float var  = sq * invN - mean * mean;
        const float sc   = gamma[j] * rsqrtf(var + kEPS);
        scsh[j]      = sc;
        scsh[HH + j] = fmaf(-mean, sc, beta[j]);
    }
}

// ---------------------------------------------------------------------------
// Kernel 3: [B][H][T] layout -> thread owns 8 consecutive t's (16B loads),
// loops h with uniform (s_load) BN constants. Fully coalesced, no shuffles.
// ---------------------------------------------------------------------------
__global__ __launch_bounds__(256) void crnn_out_kernel(
    const __half* __restrict__ buf, const float* __restrict__ scsh,
    const float* __restrict__ fcw, const float* __restrict__ fcb,
    float* __restrict__ out)
{
    const int b   = blockIdx.x;
    const int tid = threadIdx.x;
    const bool a  = (tid < TT / 8);     // 250 active
    const int t0  = tid * 8;
    const __half* bp = buf + (size_t)b * HH * TT + t0;
    const float bias = fcb[0];

    float acc[8] = {0.f, 0.f, 0.f, 0.f, 0.f, 0.f, 0.f, 0.f};
    for (int hh = 0; hh < HH; ++hh) {
        const float sc = scsh[hh], sh = scsh[HH + hh], fw = fcw[hh];
        if (a) {
            const ushort8_t v = *(const ushort8_t*)(bp + (size_t)hh * TT);
#pragma unroll
            for (int e = 0; e < 8; ++e) {
                const float vf = __half2float(__ushort_as_half((unsigned short)v[e]));
                acc[e] = fmaf(fast_tanh(fmaf(vf, sc, sh)), fw, acc[e]);
            }
        }
    }
    if (a) {
        float4* o = (float4*)(out + (size_t)b * TT + t0);
        o[0] = make_float4(acc[0] + bias, acc[1] + bias, acc[2] + bias, acc[3] + bias);
        o[1] = make_float4(acc[4] + bias, acc[5] + bias, acc[6] + bias, acc[7] + bias);
    }
}

// ---------------------------------------------------------------------------
extern "C" void kernel_launch(void* const* d_in, const int* in_sizes, int n_in,
                              void* d_out, int out_size, void* d_ws, size_t ws_size,
                              hipStream_t stream)
{
    const float* x     = (const float*)d_in[0];
    const float* Win   = (const float*)d_in[1];
    const float* Wh    = (const float*)d_in[2];
    const float* sigma = (const float*)d_in[3];
    const float* gamma = (const float*)d_in[4];
    const float* beta  = (const float*)d_in[5];
    const float* fcw   = (const float*)d_in[6];
    const float* fcb   = (const float*)d_in[7];
    float* out = (float*)d_out;

    char* ws = (char*)d_ws;
    __half* out_buf = (__half*)ws;                                   // B*H*T fp16
    float* partials = (float*)(ws + (size_t)BB * TT * HH * sizeof(__half));
    float* scsh     = (float*)((char*)partials + (size_t)BB * 2 * HH * sizeof(float));

    crnn_scan_kernel<<<BB, 256, 0, stream>>>(x, Win, Wh, sigma, out_buf, partials, out);
    crnn_bnstats_kernel<<<1, 512, 0, stream>>>(partials, gamma, beta, scsh);
    crnn_out_kernel<<<BB, 256, 0, stream>>>(out_buf, scsh, fcw, fcb, out);
}